// Round 3
// baseline (13836.697 us; speedup 1.0000x reference)
//
#include <hip/hip_runtime.h>
#include <math.h>

#define DIM  1024
#define SEQ  64
#define HDIM 256
#define NBLK 256

// ---------------- wave / block reduction helpers ----------------
__device__ __forceinline__ float wsum(float v){
  v += __shfl_xor(v, 32, 64); v += __shfl_xor(v, 16, 64); v += __shfl_xor(v, 8, 64);
  v += __shfl_xor(v, 4, 64);  v += __shfl_xor(v, 2, 64);  v += __shfl_xor(v, 1, 64);
  return v;
}
__device__ __forceinline__ float wmax(float v){
  v = fmaxf(v, __shfl_xor(v, 32, 64)); v = fmaxf(v, __shfl_xor(v, 16, 64));
  v = fmaxf(v, __shfl_xor(v, 8, 64));  v = fmaxf(v, __shfl_xor(v, 4, 64));
  v = fmaxf(v, __shfl_xor(v, 2, 64));  v = fmaxf(v, __shfl_xor(v, 1, 64));
  return v;
}
__device__ __forceinline__ float breduce(float v, float* red){
  int tid = threadIdx.x;
  v = wsum(v);
  if ((tid & 63) == 0) red[tid >> 6] = v;
  __syncthreads();
  float r = red[0] + red[1] + red[2] + red[3];
  __syncthreads();
  return r;
}

// ---------------- device-coherent (cross-XCD) access ----------------
__device__ __forceinline__ float ldc(const float* p){
  return __hip_atomic_load(p, __ATOMIC_RELAXED, __HIP_MEMORY_SCOPE_AGENT);
}
__device__ __forceinline__ void stc(float* p, float v){
  __hip_atomic_store(p, v, __ATOMIC_RELAXED, __HIP_MEMORY_SCOPE_AGENT);
}

// ---- contention-free tree barrier ----
// slots[256]: each block release-stores its epoch into its own slot.
// block 0: thread t spins (acquire) on slots[t]; when all arrive, release-store flag=ep.
// other blocks: thread 0 spins (acquire) on flag.
__device__ __forceinline__ void gsync(unsigned* slots, unsigned* flag, unsigned ep,
                                      int bid, int tid){
  __syncthreads();
  if (tid == 0)
    __hip_atomic_store(&slots[bid], ep, __ATOMIC_RELEASE, __HIP_MEMORY_SCOPE_AGENT);
  if (bid == 0){
    unsigned spins = 0;
    while (__hip_atomic_load(&slots[tid], __ATOMIC_ACQUIRE, __HIP_MEMORY_SCOPE_AGENT) < ep){
      __builtin_amdgcn_s_sleep(1);
      if (++spins > 50000000u) break;   // safety valve vs. hang
    }
    __syncthreads();
    if (tid == 0)
      __hip_atomic_store(flag, ep, __ATOMIC_RELEASE, __HIP_MEMORY_SCOPE_AGENT);
  } else {
    if (tid == 0){
      unsigned spins = 0;
      while (__hip_atomic_load(flag, __ATOMIC_ACQUIRE, __HIP_MEMORY_SCOPE_AGENT) < ep){
        __builtin_amdgcn_s_sleep(1);
        if (++spins > 50000000u) break;
      }
    }
    __syncthreads();
  }
}

// ---------------- precompute kernels ----------------
__global__ void pe_kernel(float* pe){
  int t = blockIdx.x;
  int pos = t % 30;
  for (int d = threadIdx.x; d < DIM; d += 256){
    int m = d >> 1;
    float div = __expf((float)(2 * m) * (-9.210340371976184f / 1024.0f));
    float arg = (float)pos * div;
    pe[t * DIM + d] = (d & 1) ? cosf(arg) : sinf(arg);
  }
}

__global__ void gemv_rows(const float* __restrict__ X, const float* __restrict__ W,
                          const float* __restrict__ b, float* __restrict__ Y,
                          int K, int R){
  int t = blockIdx.y;
  int r = blockIdx.x * 4 + (threadIdx.x >> 6);
  int lane = threadIdx.x & 63;
  const float* x  = X + (size_t)t * K;
  const float* wr = W + (size_t)r * K;
  float acc = 0.f;
  for (int d = lane; d < K; d += 64) acc = fmaf(wr[d], x[d], acc);
  acc = wsum(acc);
  if (lane == 0) Y[(size_t)t * R + r] = acc + b[r];
}

__global__ void matmul_nn_1024(const float* __restrict__ A, const float* __restrict__ B,
                               float* __restrict__ Cc){
  __shared__ float As[32][33];
  __shared__ float Bs[32][33];
  int tb = blockIdx.x * 32, ta = blockIdx.y * 32;
  int tx = threadIdx.x & 31, ty = threadIdx.x >> 5;
  float acc[4] = {0.f, 0.f, 0.f, 0.f};
  for (int k0 = 0; k0 < 1024; k0 += 32){
    for (int r = ty; r < 32; r += 8) As[r][tx] = A[(size_t)(ta + r) * 1024 + k0 + tx];
    for (int r = ty; r < 32; r += 8) Bs[r][tx] = B[(size_t)(k0 + r) * 1024 + tb + tx];
    __syncthreads();
    #pragma unroll
    for (int kk = 0; kk < 32; ++kk){
      float bv = Bs[kk][tx];
      #pragma unroll
      for (int m = 0; m < 4; ++m) acc[m] = fmaf(As[ty + 8 * m][kk], bv, acc[m]);
    }
    __syncthreads();
  }
  for (int m = 0; m < 4; ++m) Cc[(size_t)(ta + ty + 8 * m) * 1024 + tb + tx] = acc[m];
}

__global__ void cb_kernel(const float* __restrict__ vm_w, const float* __restrict__ vr_b,
                          const float* __restrict__ vm_b, const float* __restrict__ obj_w,
                          float* __restrict__ cb){
  int gw = blockIdx.x * 4 + (threadIdx.x >> 6);
  int lane = threadIdx.x & 63;
  const float* wr = vm_w + (size_t)gw * DIM;
  float acc = 0.f;
  for (int d = lane; d < DIM; d += 64) acc = fmaf(wr[d], vr_b[d], acc);
  acc = wsum(acc);
  if (lane == 0) cb[gw] = acc + vm_b[gw] + obj_w[(size_t)gw * 80];
}

// ---------------- the persistent autoregressive decode ----------------
struct CoopArgs {
  const float *sa_in_w, *sa_in_b, *sa_out_w, *sa_out_b;
  const float *ln1_g, *ln1_b, *ln2_g, *ln2_b, *ln3_g, *ln3_b;
  const float *ff1_w, *ff1_b, *ff2_w, *ff2_b;
  const float *vr_w, *vr_b, *obj_w;
  const float *pe, *cac, *Cm, *cb;
  float *emb, *kc, *vc, *q, *o, *u, *x2, *hb, *w;
  float *out;
  unsigned *bar;   // slots[256] at bar, flag at bar+512
};

// __launch_bounds__(256, 2): cap VGPRs at 256 -> >=2 blocks/CU occupancy, so the
// cooperative-launch co-residency check (256 blocks) can never fail on resources.
__global__ void __launch_bounds__(256, 2) decode_loop(CoopArgs a){
  const int tid = threadIdx.x, bid = blockIdx.x;
  const int wave = tid >> 6, lane = tid & 63;
  const int gw = bid * 4 + wave;            // global wave id, 0..1023
  __shared__ float smem[2048];
  __shared__ float red[8];
  unsigned* slots = a.bar;
  unsigned* flag  = a.bar + 512;
  unsigned ep = 0;

  // ---- preload this wave's hot weight rows into registers (128 floats/thread)
  float wq[16], wk[16], wv[16], wo[16], f1a[16], f1b[16], f2[32];
  {
    const float* pq = a.sa_in_w + (size_t)gw * DIM;
    const float* pk = a.sa_in_w + (size_t)(DIM + gw) * DIM;
    const float* pv = a.sa_in_w + (size_t)(2 * DIM + gw) * DIM;
    const float* po = a.sa_out_w + (size_t)gw * DIM;
    const float* p1a = a.ff1_w + (size_t)(2 * gw) * DIM;
    const float* p1b = a.ff1_w + (size_t)(2 * gw + 1) * DIM;
    const float* p2 = a.ff2_w + (size_t)gw * 2048;
    #pragma unroll
    for (int k = 0; k < 16; ++k){
      int d = lane + 64 * k;
      wq[k] = pq[d]; wk[k] = pk[d]; wv[k] = pv[d]; wo[k] = po[d];
      f1a[k] = p1a[d]; f1b[k] = p1b[d];
    }
    #pragma unroll
    for (int k = 0; k < 32; ++k) f2[k] = p2[lane + 64 * k];
  }

  // S0: emb row 0 = style
  if (bid == 0){
    for (int d = tid; d < DIM; d += 256) stc(a.emb + d, a.obj_w[(size_t)d * 80]);
  }
  ++ep; gsync(slots, flag, ep, bid, tid);

  for (int i = 0; i < SEQ; ++i){
    const float* per = a.pe + i * DIM;

    // ---- S1: QKV gemv; fill KV cache row i
    {
      float* xs = smem;
      const float* er = a.emb + (size_t)i * DIM;
      for (int t = tid; t < DIM; t += 256) xs[t] = er[t] + per[t];
      __syncthreads();
      float aq = 0.f, ak = 0.f, av = 0.f;
      #pragma unroll
      for (int k = 0; k < 16; ++k){
        float x = xs[lane + 64 * k];
        aq = fmaf(wq[k], x, aq);
        ak = fmaf(wk[k], x, ak);
        av = fmaf(wv[k], x, av);
      }
      aq = wsum(aq); ak = wsum(ak); av = wsum(av);
      if (lane == 0){
        stc(a.q + gw, aq + a.sa_in_b[gw]);
        stc(a.kc + (size_t)i * DIM + gw, ak + a.sa_in_b[DIM + gw]);
        stc(a.vc + (size_t)i * DIM + gw, av + a.sa_in_b[2 * DIM + gw]);
      }
    }
    ++ep; gsync(slots, flag, ep, bid, tid);

    // ---- S2: self-attention row i (blocks 0..3, one head each)
    if (bid < 4){
      const int h = bid;
      float* qs  = smem;        // 256
      float* scp = smem + 256;  // 64
      qs[tid] = ldc(a.q + h * HDIM + tid);
      __syncthreads();
      for (int j = wave; j <= i; j += 4){
        const float* kr = a.kc + (size_t)j * DIM + h * HDIM;
        float s = 0.f;
        s = fmaf(qs[lane      ], kr[lane      ], s);
        s = fmaf(qs[lane +  64], kr[lane +  64], s);
        s = fmaf(qs[lane + 128], kr[lane + 128], s);
        s = fmaf(qs[lane + 192], kr[lane + 192], s);
        s = wsum(s);
        if (lane == 0){
          float slope = 1.0f / (float)(4 << (2 * h));   // 0.25^(h+1)
          scp[j] = s * 0.0625f - slope * (float)((i - j) / 30);
        }
      }
      __syncthreads();
      if (wave == 0){
        float s = (lane <= i) ? scp[lane] : -3.0e38f;
        float mx = wmax(s);
        float p = (lane <= i) ? __expf(s - mx) : 0.f;
        float sum = wsum(p);
        scp[lane] = p / sum;
      }
      __syncthreads();
      {
        float acc = 0.f;
        const float* vb = a.vc + h * HDIM + tid;
        for (int j = 0; j <= i; ++j) acc = fmaf(scp[j], vb[(size_t)j * DIM], acc);
        stc(a.o + h * HDIM + tid, acc);
      }
    }
    ++ep; gsync(slots, flag, ep, bid, tid);

    // ---- S3: u = x + o @ sa_out_w.T + b
    {
      float* os = smem;
      for (int t = tid; t < DIM; t += 256) os[t] = ldc(a.o + t);
      __syncthreads();
      float acc = 0.f;
      #pragma unroll
      for (int k = 0; k < 16; ++k) acc = fmaf(wo[k], os[lane + 64 * k], acc);
      acc = wsum(acc);
      if (lane == 0){
        float x = a.emb[(size_t)i * DIM + gw] + per[gw];
        stc(a.u + gw, x + acc + a.sa_out_b[gw]);
      }
    }
    ++ep; gsync(slots, flag, ep, bid, tid);

    // ---- S4: ln1 -> +ca_contrib -> ln2 -> x2; ff1 + relu
    {
      float* xs = smem;
      for (int t = tid; t < DIM; t += 256) xs[t] = ldc(a.u + t);
      __syncthreads();
      float s0 = 0.f;
      #pragma unroll
      for (int k = 0; k < 4; ++k) s0 += xs[tid + 256 * k];
      float mean = breduce(s0, red) * (1.f / 1024.f);
      float s1 = 0.f;
      #pragma unroll
      for (int k = 0; k < 4; ++k){ float dd = xs[tid + 256 * k] - mean; s1 = fmaf(dd, dd, s1); }
      float var = breduce(s1, red) * (1.f / 1024.f);
      float rs = 1.f / sqrtf(var + 1e-5f);
      float tv[4];
      #pragma unroll
      for (int k = 0; k < 4; ++k){
        int d = tid + 256 * k;
        float x1 = (xs[d] - mean) * rs * a.ln1_g[d] + a.ln1_b[d];
        tv[k] = x1 + a.cac[(size_t)i * DIM + d];
      }
      float t0 = tv[0] + tv[1] + tv[2] + tv[3];
      float mean2 = breduce(t0, red) * (1.f / 1024.f);
      float t1 = 0.f;
      #pragma unroll
      for (int k = 0; k < 4; ++k){ float dd = tv[k] - mean2; t1 = fmaf(dd, dd, t1); }
      float var2 = breduce(t1, red) * (1.f / 1024.f);
      float rs2 = 1.f / sqrtf(var2 + 1e-5f);
      #pragma unroll
      for (int k = 0; k < 4; ++k){
        int d = tid + 256 * k;
        xs[d] = (tv[k] - mean2) * rs2 * a.ln2_g[d] + a.ln2_b[d];
      }
      __syncthreads();
      if (bid == 0){
        for (int t = tid; t < DIM; t += 256) stc(a.x2 + t, xs[t]);
      }
      // ff1: rows 2*gw, 2*gw+1
      float acc0 = 0.f, acc1 = 0.f;
      #pragma unroll
      for (int k = 0; k < 16; ++k){
        float x = xs[lane + 64 * k];
        acc0 = fmaf(f1a[k], x, acc0);
        acc1 = fmaf(f1b[k], x, acc1);
      }
      acc0 = wsum(acc0); acc1 = wsum(acc1);
      if (lane == 0){
        stc(a.hb + 2 * gw,     fmaxf(acc0 + a.ff1_b[2 * gw], 0.f));
        stc(a.hb + 2 * gw + 1, fmaxf(acc1 + a.ff1_b[2 * gw + 1], 0.f));
      }
    }
    ++ep; gsync(slots, flag, ep, bid, tid);

    // ---- S5: w = x2 + h @ ff2_w.T + b
    {
      float* hsm = smem;
      for (int t = tid; t < 2048; t += 256) hsm[t] = ldc(a.hb + t);
      __syncthreads();
      float x2v = (lane == 0) ? ldc(a.x2 + gw) : 0.f;
      float acc = 0.f;
      #pragma unroll
      for (int k = 0; k < 32; ++k) acc = fmaf(f2[k], hsm[lane + 64 * k], acc);
      acc = wsum(acc);
      if (lane == 0) stc(a.w + gw, x2v + acc + a.ff2_b[gw]);
    }
    ++ep; gsync(slots, flag, ep, bid, tid);

    // ---- S6: ln3; final-output row i; recurrence new_tok -> emb[i+1]
    {
      float* xs = smem;
      for (int t = tid; t < DIM; t += 256) xs[t] = ldc(a.w + t);
      __syncthreads();
      float s0 = 0.f;
      #pragma unroll
      for (int k = 0; k < 4; ++k) s0 += xs[tid + 256 * k];
      float mean = breduce(s0, red) * (1.f / 1024.f);
      float s1 = 0.f;
      #pragma unroll
      for (int k = 0; k < 4; ++k){ float dd = xs[tid + 256 * k] - mean; s1 = fmaf(dd, dd, s1); }
      float var = breduce(s1, red) * (1.f / 1024.f);
      float rs = 1.f / sqrtf(var + 1e-5f);
      float ov[4];
      #pragma unroll
      for (int k = 0; k < 4; ++k){
        int d = tid + 256 * k;
        ov[k] = (xs[d] - mean) * rs * a.ln3_g[d] + a.ln3_b[d];
      }
      __syncthreads();
      #pragma unroll
      for (int k = 0; k < 4; ++k) xs[tid + 256 * k] = ov[k];
      __syncthreads();
      {
        const float* pr = a.vr_w + (size_t)gw * DIM;   // streamed (L2-resident)
        const float* pc = a.Cm + (size_t)gw * DIM;
        float ar = 0.f, ac = 0.f;
        #pragma unroll
        for (int k = 0; k < 16; ++k){
          float x = xs[lane + 64 * k];
          ar = fmaf(pr[lane + 64 * k], x, ar);
          ac = fmaf(pc[lane + 64 * k], x, ac);
        }
        ar = wsum(ar); ac = wsum(ac);
        if (lane == 0){
          a.out[(size_t)i * DIM + gw] = ar + a.vr_b[gw];
          if (i < SEQ - 1) stc(a.emb + (size_t)(i + 1) * DIM + gw, ac + a.cb[gw]);
        }
      }
    }
    ++ep; gsync(slots, flag, ep, bid, tid);
  }
}

// ---------------- host launcher ----------------
extern "C" void kernel_launch(void* const* d_in, const int* in_sizes, int n_in,
                              void* d_out, int out_size, void* d_ws, size_t ws_size,
                              hipStream_t stream){
  const float* hs       = (const float*)d_in[0];
  const float* hid_w    = (const float*)d_in[1];
  const float* hid_b    = (const float*)d_in[2];
  const float* obj_w    = (const float*)d_in[3];
  const float* sa_in_w  = (const float*)d_in[4];
  const float* sa_in_b  = (const float*)d_in[5];
  const float* sa_out_w = (const float*)d_in[6];
  const float* sa_out_b = (const float*)d_in[7];
  const float* ca_in_w  = (const float*)d_in[8];
  const float* ca_in_b  = (const float*)d_in[9];
  const float* ca_out_w = (const float*)d_in[10];
  const float* ca_out_b = (const float*)d_in[11];
  const float* ln1_g    = (const float*)d_in[12];
  const float* ln1_b    = (const float*)d_in[13];
  const float* ln2_g    = (const float*)d_in[14];
  const float* ln2_b    = (const float*)d_in[15];
  const float* ln3_g    = (const float*)d_in[16];
  const float* ln3_b    = (const float*)d_in[17];
  const float* ff1_w    = (const float*)d_in[18];
  const float* ff1_b    = (const float*)d_in[19];
  const float* ff2_w    = (const float*)d_in[20];
  const float* ff2_b    = (const float*)d_in[21];
  const float* vr_w     = (const float*)d_in[22];
  const float* vr_b     = (const float*)d_in[23];
  const float* vm_w     = (const float*)d_in[24];
  const float* vm_b     = (const float*)d_in[25];

  float* ws = (float*)d_ws;
  float* pe   = ws;                 // 65536
  float* emb  = ws + 65536;         // 65536
  float* kc   = ws + 131072;        // 65536
  float* vc   = ws + 196608;        // 65536
  float* mem  = ws + 262144;        // 65536
  float* vtmp = ws + 327680;        // 65536
  float* cac  = ws + 393216;        // 65536
  float* Cm   = ws + 458752;        // 1048576
  float* q    = ws + 1507328;       // 1024
  float* o    = ws + 1508352;       // 1024
  float* u    = ws + 1509376;       // 1024
  float* x2   = ws + 1510400;       // 1024
  float* hb   = ws + 1511424;       // 2048
  float* wv   = ws + 1513472;       // 1024
  float* cb   = ws + 1514496;       // 1024
  unsigned* bar = (unsigned*)(ws + 1515520);  // slots[256] + flag (4KB)

  hipMemsetAsync((void*)bar, 0, 4096, stream);

  pe_kernel<<<SEQ, 256, 0, stream>>>(pe);
  // mem = hs @ hid_w.T + hid_b
  gemv_rows<<<dim3(256, SEQ), 256, 0, stream>>>(hs, hid_w, hid_b, mem, 1024, 1024);
  // v = mem @ ca_wv.T + ca_bv   (cross-attention collapses to V)
  gemv_rows<<<dim3(256, SEQ), 256, 0, stream>>>(mem, ca_in_w + 2048 * 1024, ca_in_b + 2048, vtmp, 1024, 1024);
  // ca_contrib = v @ ca_out_w.T + ca_out_b
  gemv_rows<<<dim3(256, SEQ), 256, 0, stream>>>(vtmp, ca_out_w, ca_out_b, cac, 1024, 1024);
  // C = vm_w @ vr_w  (folds the two recurrence gemvs into one)
  matmul_nn_1024<<<dim3(32, 32), 256, 0, stream>>>(vm_w, vr_w, Cm);
  // cb = vm_w @ vr_b + vm_b + style
  cb_kernel<<<256, 256, 0, stream>>>(vm_w, vr_b, vm_b, obj_w, cb);

  CoopArgs A;
  A.sa_in_w = sa_in_w; A.sa_in_b = sa_in_b; A.sa_out_w = sa_out_w; A.sa_out_b = sa_out_b;
  A.ln1_g = ln1_g; A.ln1_b = ln1_b; A.ln2_g = ln2_g; A.ln2_b = ln2_b; A.ln3_g = ln3_g; A.ln3_b = ln3_b;
  A.ff1_w = ff1_w; A.ff1_b = ff1_b; A.ff2_w = ff2_w; A.ff2_b = ff2_b;
  A.vr_w = vr_w; A.vr_b = vr_b; A.obj_w = obj_w;
  A.pe = pe; A.cac = cac; A.Cm = Cm; A.cb = cb;
  A.emb = emb; A.kc = kc; A.vc = vc; A.q = q; A.o = o; A.u = u; A.x2 = x2; A.hb = hb; A.w = wv;
  A.out = (float*)d_out;
  A.bar = bar;

  void* params[1] = { &A };
  hipError_t e = hipLaunchCooperativeKernel((void*)decode_loop, dim3(NBLK), dim3(256), params, 0, stream);
  if (e != hipSuccess){
    // fallback: plain launch; 256 blocks at >=1 block/CU are co-resident on 256 CUs
    decode_loop<<<dim3(NBLK), dim3(256), 0, stream>>>(A);
  }
}

// Round 4
// 3477.793 us; speedup vs baseline: 3.9786x; 3.9786x over previous
//
#include <hip/hip_runtime.h>
#include <math.h>

#define DIM  1024
#define SEQ  64
#define HDIM 256
#define NBLK 256

// ---------------- wave / block reduction helpers ----------------
__device__ __forceinline__ float wsum(float v){
  v += __shfl_xor(v, 32, 64); v += __shfl_xor(v, 16, 64); v += __shfl_xor(v, 8, 64);
  v += __shfl_xor(v, 4, 64);  v += __shfl_xor(v, 2, 64);  v += __shfl_xor(v, 1, 64);
  return v;
}
__device__ __forceinline__ float wmax(float v){
  v = fmaxf(v, __shfl_xor(v, 32, 64)); v = fmaxf(v, __shfl_xor(v, 16, 64));
  v = fmaxf(v, __shfl_xor(v, 8, 64));  v = fmaxf(v, __shfl_xor(v, 4, 64));
  v = fmaxf(v, __shfl_xor(v, 2, 64));  v = fmaxf(v, __shfl_xor(v, 1, 64));
  return v;
}
__device__ __forceinline__ float breduce(float v, float* red){
  int tid = threadIdx.x;
  v = wsum(v);
  if ((tid & 63) == 0) red[tid >> 6] = v;
  __syncthreads();
  float r = red[0] + red[1] + red[2] + red[3];
  __syncthreads();
  return r;
}

// ---------------- device-coherent (cross-XCD) payload access ----------------
// relaxed agent atomics carry the sc-bits that bypass L1/L2 to the LLC
__device__ __forceinline__ float ldc(const float* p){
  return __hip_atomic_load(p, __ATOMIC_RELAXED, __HIP_MEMORY_SCOPE_AGENT);
}
__device__ __forceinline__ void stc(float* p, float v){
  __hip_atomic_store(p, v, __ATOMIC_RELAXED, __HIP_MEMORY_SCOPE_AGENT);
}

// hedged spin: relaxed polls (no cache-invalidate traffic); acquire fallback
// after 8192 polls in case relaxed visibility assumption fails (no livelock).
__device__ __forceinline__ void spin_ge(unsigned* p, unsigned ep){
  unsigned spins = 0;
  while (__hip_atomic_load(p, __ATOMIC_RELAXED, __HIP_MEMORY_SCOPE_AGENT) < ep){
    if (++spins > 8192u){
      unsigned s2 = 0;
      while (__hip_atomic_load(p, __ATOMIC_ACQUIRE, __HIP_MEMORY_SCOPE_AGENT) < ep){
        __builtin_amdgcn_s_sleep(2);
        if (++s2 > 100000000u) break;
      }
      return;
    }
  }
}

// tree barrier: blocks 1..255 release-store slot[bid]; block0 threads spin on
// slots (relaxed), then release-store flag; others spin flag (relaxed).
__device__ __forceinline__ void gsync(unsigned* slots, unsigned* flag, unsigned ep,
                                      int bid, int tid){
  __syncthreads();
  if (bid == 0){
    if (tid > 0) spin_ge(&slots[tid], ep);    // block0's own arrival is implicit
    __syncthreads();
    if (tid == 0)
      __hip_atomic_store(flag, ep, __ATOMIC_RELEASE, __HIP_MEMORY_SCOPE_AGENT);
  } else {
    if (tid == 0){
      __hip_atomic_store(&slots[bid], ep, __ATOMIC_RELEASE, __HIP_MEMORY_SCOPE_AGENT);
      spin_ge(flag, ep);
    }
    __syncthreads();
  }
  asm volatile("" ::: "memory");
}

// ---------------- precompute kernels ----------------
__global__ void pe_kernel(float* pe){
  int t = blockIdx.x;
  int pos = t % 30;
  for (int d = threadIdx.x; d < DIM; d += 256){
    int m = d >> 1;
    float div = __expf((float)(2 * m) * (-9.210340371976184f / 1024.0f));
    float arg = (float)pos * div;
    pe[t * DIM + d] = (d & 1) ? cosf(arg) : sinf(arg);
  }
}

__global__ void gemv_rows(const float* __restrict__ X, const float* __restrict__ W,
                          const float* __restrict__ b, float* __restrict__ Y,
                          int K, int R){
  int t = blockIdx.y;
  int r = blockIdx.x * 4 + (threadIdx.x >> 6);
  int lane = threadIdx.x & 63;
  const float* x  = X + (size_t)t * K;
  const float* wr = W + (size_t)r * K;
  float acc = 0.f;
  for (int d = lane; d < K; d += 64) acc = fmaf(wr[d], x[d], acc);
  acc = wsum(acc);
  if (lane == 0) Y[(size_t)t * R + r] = acc + b[r];
}

__global__ void matmul_nn_1024(const float* __restrict__ A, const float* __restrict__ B,
                               float* __restrict__ Cc){
  __shared__ float As[32][33];
  __shared__ float Bs[32][33];
  int tb = blockIdx.x * 32, ta = blockIdx.y * 32;
  int tx = threadIdx.x & 31, ty = threadIdx.x >> 5;
  float acc[4] = {0.f, 0.f, 0.f, 0.f};
  for (int k0 = 0; k0 < 1024; k0 += 32){
    for (int r = ty; r < 32; r += 8) As[r][tx] = A[(size_t)(ta + r) * 1024 + k0 + tx];
    for (int r = ty; r < 32; r += 8) Bs[r][tx] = B[(size_t)(k0 + r) * 1024 + tb + tx];
    __syncthreads();
    #pragma unroll
    for (int kk = 0; kk < 32; ++kk){
      float bv = Bs[kk][tx];
      #pragma unroll
      for (int m = 0; m < 4; ++m) acc[m] = fmaf(As[ty + 8 * m][kk], bv, acc[m]);
    }
    __syncthreads();
  }
  for (int m = 0; m < 4; ++m) Cc[(size_t)(ta + ty + 8 * m) * 1024 + tb + tx] = acc[m];
}

__global__ void cb_kernel(const float* __restrict__ vm_w, const float* __restrict__ vr_b,
                          const float* __restrict__ vm_b, const float* __restrict__ obj_w,
                          float* __restrict__ cb){
  int gw = blockIdx.x * 4 + (threadIdx.x >> 6);
  int lane = threadIdx.x & 63;
  const float* wr = vm_w + (size_t)gw * DIM;
  float acc = 0.f;
  for (int d = lane; d < DIM; d += 64) acc = fmaf(wr[d], vr_b[d], acc);
  acc = wsum(acc);
  if (lane == 0) cb[gw] = acc + vm_b[gw] + obj_w[(size_t)gw * 80];
}

// ---------------- the persistent autoregressive decode ----------------
struct CoopArgs {
  const float *sa_in_w, *sa_in_b, *sa_out_w, *sa_out_b;
  const float *ln1_g, *ln1_b, *ln2_g, *ln2_b, *ln3_g, *ln3_b;
  const float *ff1_w, *ff1_b, *ff2_w, *ff2_b;
  const float *vr_w, *vr_b, *obj_w;
  const float *pe, *cac, *Cm, *cb;
  float *emb, *kct, *vc, *q, *u, *hb, *w;
  float *out;
  unsigned *bar;   // slots[256] at bar, flag at bar+320
};

__global__ void __launch_bounds__(256, 2) decode_loop(CoopArgs a){
  const int tid = threadIdx.x, bid = blockIdx.x;
  const int wave = tid >> 6, lane = tid & 63;
  const int gw = bid * 4 + wave;            // global wave id / output row, 0..1023
  __shared__ float sm[2048];
  __shared__ float scp[256];                // softmax probs [head][64]
  __shared__ float red[8];
  unsigned* slots = a.bar;
  unsigned* flag  = a.bar + 320;
  unsigned ep = 0;

  // ---- preload this wave's hot weight rows (128 floats/thread -> VGPR/AGPR)
  float wq[16], wk[16], wv[16], wo[16], f1a[16], f1b[16], f2[32];
  {
    const float* pq = a.sa_in_w + (size_t)gw * DIM;
    const float* pk = a.sa_in_w + (size_t)(DIM + gw) * DIM;
    const float* pv = a.sa_in_w + (size_t)(2 * DIM + gw) * DIM;
    const float* po = a.sa_out_w + (size_t)gw * DIM;
    const float* p1a = a.ff1_w + (size_t)(2 * gw) * DIM;
    const float* p1b = a.ff1_w + (size_t)(2 * gw + 1) * DIM;
    const float* p2 = a.ff2_w + (size_t)gw * 2048;
    #pragma unroll
    for (int k = 0; k < 16; ++k){
      int d = lane + 64 * k;
      wq[k] = pq[d]; wk[k] = pk[d]; wv[k] = pv[d]; wo[k] = po[d];
      f1a[k] = p1a[d]; f1b[k] = p1b[d];
    }
    #pragma unroll
    for (int k = 0; k < 32; ++k) f2[k] = p2[lane + 64 * k];
  }

  // S0: emb row 0 = style
  if (bid == 0){
    for (int d = tid; d < DIM; d += 256) stc(a.emb + d, a.obj_w[(size_t)d * 80]);
  }
  ++ep; gsync(slots, flag, ep, bid, tid);

  for (int i = 0; i < SEQ; ++i){
    const float* per = a.pe + i * DIM;

    // ---- S1: QKV gemv; fill KV cache row i (kct transposed: [dim][64])
    {
      float* xs = sm;
      const float* er = a.emb + (size_t)i * DIM;
      for (int t = tid; t < DIM; t += 256) xs[t] = ldc(er + t) + per[t];
      __syncthreads();
      float aq = 0.f, ak = 0.f, av = 0.f;
      #pragma unroll
      for (int k = 0; k < 16; ++k){
        float x = xs[lane + 64 * k];
        aq = fmaf(wq[k], x, aq);
        ak = fmaf(wk[k], x, ak);
        av = fmaf(wv[k], x, av);
      }
      aq = wsum(aq); ak = wsum(ak); av = wsum(av);
      if (lane == 0){
        stc(a.q + gw, aq + a.sa_in_b[gw]);
        stc(a.kct + (size_t)gw * 64 + i, ak + a.sa_in_b[DIM + gw]);
        stc(a.vc + (size_t)i * DIM + gw, av + a.sa_in_b[2 * DIM + gw]);
      }
      __syncthreads();
    }
    ++ep; gsync(slots, flag, ep, bid, tid);

    // ---- S2: full attention (all blocks, redundant) + out-proj row gw -> u
    {
      float* qs = sm;   // 1024; reused as os after scores are done
      for (int t = tid; t < DIM; t += 256) qs[t] = ldc(a.q + t);
      __syncthreads();
      // scores: wave = head, lane = key index j
      const int h = wave;
      float s;
      if (lane <= i){
        const float* kp = a.kct + ((size_t)h * 256) * 64 + lane;
        float acc = 0.f;
        #pragma unroll 8
        for (int d = 0; d < 256; ++d) acc = fmaf(qs[h * 256 + d], ldc(kp + d * 64), acc);
        float slope = 1.0f / (float)(4 << (2 * h));   // 0.25^(h+1)
        s = acc * 0.0625f - slope * (float)((i - lane) / 30);
      } else {
        s = -3.0e38f;
      }
      float mx = wmax(s);
      float p = (lane <= i) ? __expf(s - mx) : 0.f;
      float sum = wsum(p);
      scp[h * 64 + lane] = p / sum;
      __syncthreads();
      // PV: thread owns dims tid+256m (head m); o into os (= sm, qs dead)
      float o0 = 0.f, o1 = 0.f, o2 = 0.f, o3 = 0.f;
      for (int j = 0; j <= i; ++j){
        const float* vrow = a.vc + (size_t)j * DIM;
        float p0 = scp[j], p1 = scp[64 + j], p2 = scp[128 + j], p3 = scp[192 + j];
        o0 = fmaf(p0, ldc(vrow + tid), o0);
        o1 = fmaf(p1, ldc(vrow + 256 + tid), o1);
        o2 = fmaf(p2, ldc(vrow + 512 + tid), o2);
        o3 = fmaf(p3, ldc(vrow + 768 + tid), o3);
      }
      __syncthreads();
      float* os = sm;
      os[tid] = o0; os[tid + 256] = o1; os[tid + 512] = o2; os[tid + 768] = o3;
      __syncthreads();
      // out-proj row gw + residual
      float acc = 0.f;
      #pragma unroll
      for (int k = 0; k < 16; ++k) acc = fmaf(wo[k], os[lane + 64 * k], acc);
      acc = wsum(acc);
      if (lane == 0){
        float x = ldc(a.emb + (size_t)i * DIM + gw) + per[gw];
        stc(a.u + gw, x + acc + a.sa_out_b[gw]);
      }
      __syncthreads();
    }
    ++ep; gsync(slots, flag, ep, bid, tid);

    // ---- S3: ln1 -> +ca_contrib -> ln2 (local) ; ff1 rows -> hb
    float x2v;
    {
      float* xs = sm;
      for (int t = tid; t < DIM; t += 256) xs[t] = ldc(a.u + t);
      __syncthreads();
      float s0 = 0.f;
      #pragma unroll
      for (int k = 0; k < 4; ++k) s0 += xs[tid + 256 * k];
      float mean = breduce(s0, red) * (1.f / 1024.f);
      float s1 = 0.f;
      #pragma unroll
      for (int k = 0; k < 4; ++k){ float dd = xs[tid + 256 * k] - mean; s1 = fmaf(dd, dd, s1); }
      float var = breduce(s1, red) * (1.f / 1024.f);
      float rs = 1.f / sqrtf(var + 1e-5f);
      float tv[4];
      #pragma unroll
      for (int k = 0; k < 4; ++k){
        int d = tid + 256 * k;
        float x1 = (xs[d] - mean) * rs * a.ln1_g[d] + a.ln1_b[d];
        tv[k] = x1 + a.cac[(size_t)i * DIM + d];
      }
      float t0 = tv[0] + tv[1] + tv[2] + tv[3];
      float mean2 = breduce(t0, red) * (1.f / 1024.f);
      float t1 = 0.f;
      #pragma unroll
      for (int k = 0; k < 4; ++k){ float dd = tv[k] - mean2; t1 = fmaf(dd, dd, t1); }
      float var2 = breduce(t1, red) * (1.f / 1024.f);
      float rs2 = 1.f / sqrtf(var2 + 1e-5f);
      #pragma unroll
      for (int k = 0; k < 4; ++k){
        int d = tid + 256 * k;
        xs[d] = (tv[k] - mean2) * rs2 * a.ln2_g[d] + a.ln2_b[d];
      }
      __syncthreads();
      x2v = xs[gw];   // this wave's x2 element, kept in-register for S4
      float acc0 = 0.f, acc1 = 0.f;
      #pragma unroll
      for (int k = 0; k < 16; ++k){
        float x = xs[lane + 64 * k];
        acc0 = fmaf(f1a[k], x, acc0);
        acc1 = fmaf(f1b[k], x, acc1);
      }
      acc0 = wsum(acc0); acc1 = wsum(acc1);
      if (lane == 0){
        stc(a.hb + 2 * gw,     fmaxf(acc0 + a.ff1_b[2 * gw], 0.f));
        stc(a.hb + 2 * gw + 1, fmaxf(acc1 + a.ff1_b[2 * gw + 1], 0.f));
      }
      __syncthreads();
    }
    ++ep; gsync(slots, flag, ep, bid, tid);

    // ---- S4: w = x2 + h @ ff2_w.T + b
    {
      float* hsm = sm;
      for (int t = tid; t < 2048; t += 256) hsm[t] = ldc(a.hb + t);
      __syncthreads();
      float acc = 0.f;
      #pragma unroll
      for (int k = 0; k < 32; ++k) acc = fmaf(f2[k], hsm[lane + 64 * k], acc);
      acc = wsum(acc);
      if (lane == 0) stc(a.w + gw, x2v + acc + a.ff2_b[gw]);
      __syncthreads();
    }
    ++ep; gsync(slots, flag, ep, bid, tid);

    // ---- S5: ln3; final-output row i; recurrence new_tok -> emb[i+1]
    {
      float* xs = sm;
      for (int t = tid; t < DIM; t += 256) xs[t] = ldc(a.w + t);
      __syncthreads();
      float s0 = 0.f;
      #pragma unroll
      for (int k = 0; k < 4; ++k) s0 += xs[tid + 256 * k];
      float mean = breduce(s0, red) * (1.f / 1024.f);
      float s1 = 0.f;
      #pragma unroll
      for (int k = 0; k < 4; ++k){ float dd = xs[tid + 256 * k] - mean; s1 = fmaf(dd, dd, s1); }
      float var = breduce(s1, red) * (1.f / 1024.f);
      float rs = 1.f / sqrtf(var + 1e-5f);
      float ov[4];
      #pragma unroll
      for (int k = 0; k < 4; ++k){
        int d = tid + 256 * k;
        ov[k] = (xs[d] - mean) * rs * a.ln3_g[d] + a.ln3_b[d];
      }
      __syncthreads();
      #pragma unroll
      for (int k = 0; k < 4; ++k) xs[tid + 256 * k] = ov[k];
      __syncthreads();
      {
        const float* pr = a.vr_w + (size_t)gw * DIM;   // streamed; L2 stays warm now
        const float* pc = a.Cm + (size_t)gw * DIM;
        float ar = 0.f, ac = 0.f;
        #pragma unroll
        for (int k = 0; k < 16; ++k){
          float x = xs[lane + 64 * k];
          ar = fmaf(pr[lane + 64 * k], x, ar);
          ac = fmaf(pc[lane + 64 * k], x, ac);
        }
        ar = wsum(ar); ac = wsum(ac);
        if (lane == 0){
          a.out[(size_t)i * DIM + gw] = ar + a.vr_b[gw];
          if (i < SEQ - 1) stc(a.emb + (size_t)(i + 1) * DIM + gw, ac + a.cb[gw]);
        }
      }
      __syncthreads();
    }
    ++ep; gsync(slots, flag, ep, bid, tid);
  }
}

// ---------------- host launcher ----------------
extern "C" void kernel_launch(void* const* d_in, const int* in_sizes, int n_in,
                              void* d_out, int out_size, void* d_ws, size_t ws_size,
                              hipStream_t stream){
  const float* hs       = (const float*)d_in[0];
  const float* hid_w    = (const float*)d_in[1];
  const float* hid_b    = (const float*)d_in[2];
  const float* obj_w    = (const float*)d_in[3];
  const float* sa_in_w  = (const float*)d_in[4];
  const float* sa_in_b  = (const float*)d_in[5];
  const float* sa_out_w = (const float*)d_in[6];
  const float* sa_out_b = (const float*)d_in[7];
  const float* ca_in_w  = (const float*)d_in[8];
  const float* ca_in_b  = (const float*)d_in[9];
  const float* ca_out_w = (const float*)d_in[10];
  const float* ca_out_b = (const float*)d_in[11];
  const float* ln1_g    = (const float*)d_in[12];
  const float* ln1_b    = (const float*)d_in[13];
  const float* ln2_g    = (const float*)d_in[14];
  const float* ln2_b    = (const float*)d_in[15];
  const float* ln3_g    = (const float*)d_in[16];
  const float* ln3_b    = (const float*)d_in[17];
  const float* ff1_w    = (const float*)d_in[18];
  const float* ff1_b    = (const float*)d_in[19];
  const float* ff2_w    = (const float*)d_in[20];
  const float* ff2_b    = (const float*)d_in[21];
  const float* vr_w     = (const float*)d_in[22];
  const float* vr_b     = (const float*)d_in[23];
  const float* vm_w     = (const float*)d_in[24];
  const float* vm_b     = (const float*)d_in[25];

  float* ws = (float*)d_ws;
  float* pe   = ws;                 // 65536
  float* emb  = ws + 65536;         // 65536
  float* kct  = ws + 131072;        // 65536 (transposed: [dim][64])
  float* vc   = ws + 196608;        // 65536
  float* mem  = ws + 262144;        // 65536
  float* vtmp = ws + 327680;        // 65536
  float* cac  = ws + 393216;        // 65536
  float* Cm   = ws + 458752;        // 1048576
  float* q    = ws + 1507328;       // 1024
  float* u    = ws + 1508352;       // 1024
  float* hb   = ws + 1509376;       // 2048
  float* wv   = ws + 1511424;       // 1024
  float* cb   = ws + 1512448;       // 1024
  unsigned* bar = (unsigned*)(ws + 1513472);  // 4KB: slots[256] + flag @ +320

  hipMemsetAsync((void*)bar, 0, 4096, stream);

  pe_kernel<<<SEQ, 256, 0, stream>>>(pe);
  // mem = hs @ hid_w.T + hid_b
  gemv_rows<<<dim3(256, SEQ), 256, 0, stream>>>(hs, hid_w, hid_b, mem, 1024, 1024);
  // v = mem @ ca_wv.T + ca_bv   (cross-attention collapses to V)
  gemv_rows<<<dim3(256, SEQ), 256, 0, stream>>>(mem, ca_in_w + 2048 * 1024, ca_in_b + 2048, vtmp, 1024, 1024);
  // ca_contrib = v @ ca_out_w.T + ca_out_b
  gemv_rows<<<dim3(256, SEQ), 256, 0, stream>>>(vtmp, ca_out_w, ca_out_b, cac, 1024, 1024);
  // C = vm_w @ vr_w  (folds the two recurrence gemvs into one)
  matmul_nn_1024<<<dim3(32, 32), 256, 0, stream>>>(vm_w, vr_w, Cm);
  // cb = vm_w @ vr_b + vm_b + style
  cb_kernel<<<256, 256, 0, stream>>>(vm_w, vr_b, vm_b, obj_w, cb);

  CoopArgs A;
  A.sa_in_w = sa_in_w; A.sa_in_b = sa_in_b; A.sa_out_w = sa_out_w; A.sa_out_b = sa_out_b;
  A.ln1_g = ln1_g; A.ln1_b = ln1_b; A.ln2_g = ln2_g; A.ln2_b = ln2_b; A.ln3_g = ln3_g; A.ln3_b = ln3_b;
  A.ff1_w = ff1_w; A.ff1_b = ff1_b; A.ff2_w = ff2_w; A.ff2_b = ff2_b;
  A.vr_w = vr_w; A.vr_b = vr_b; A.obj_w = obj_w;
  A.pe = pe; A.cac = cac; A.Cm = Cm; A.cb = cb;
  A.emb = emb; A.kct = kct; A.vc = vc; A.q = q; A.u = u; A.hb = hb; A.w = wv;
  A.out = (float*)d_out;
  A.bar = bar;

  void* params[1] = { &A };
  hipError_t e = hipLaunchCooperativeKernel((void*)decode_loop, dim3(NBLK), dim3(256), params, 0, stream);
  if (e != hipSuccess){
    decode_loop<<<dim3(NBLK), dim3(256), 0, stream>>>(A);
  }
}